// Round 4
// baseline (769.298 us; speedup 1.0000x reference)
//
#include <hip/hip_runtime.h>
#include <math.h>

// ---------------------------------------------------------------------------
// SPA graph conv, 2 layers. N=50000, E=800000, C=128, OUT=64, HS=16, K=4.
// R4: SLICE-MAJOR activation layout X[slice][node][16ch] (slice = contiguous
//     3.2MB block, fits one XCD's 4MB L2). Gather kernels pick slice by
//     blockIdx&7 (XCD round-robin). csr/alpha streamed with nontemporal
//     loads to avoid evicting the hot slice. All fp32.
// ---------------------------------------------------------------------------

__device__ __forceinline__ float wave_max(float v) {
#pragma unroll
  for (int o = 32; o; o >>= 1) v = fmaxf(v, __shfl_xor(v, o, 64));
  return v;
}
__device__ __forceinline__ float wave_sum(float v) {
#pragma unroll
  for (int o = 32; o; o >>= 1) v += __shfl_xor(v, o, 64);
  return v;
}

// sliced address of (row r, channel c): slice = c>>4, within = c&15
__device__ __forceinline__ long sl_addr(long r, int c, long sstr) {
  return (long)(c >> 4) * sstr + r * 16 + (c & 15);
}

// ---------------------------------------------------------------------------
// GEMM: Y[r][c] = sum_k X[r][k]*W[c][k] + bias[c].  K fixed = 128.
// INS/OUTS select row-major vs slice-major layout for X / Y.
// ---------------------------------------------------------------------------
template <int COLS, bool INS, bool OUTS>
__global__ __launch_bounds__(256) void gemm_bias(
    const float* __restrict__ X, const float* __restrict__ W,
    const float* __restrict__ bias, float* __restrict__ Y, int nrows,
    long sstr) {
  __shared__ float Wt[128 * COLS];
  const int t = threadIdx.x;
  for (int q = t; q < COLS * 32; q += 256) {
    const int c = q >> 5;
    const int k0 = (q & 31) << 2;
    const float4 w = *(const float4*)(W + c * 128 + k0);
    Wt[(k0 + 0) * COLS + c] = w.x;
    Wt[(k0 + 1) * COLS + c] = w.y;
    Wt[(k0 + 2) * COLS + c] = w.z;
    Wt[(k0 + 3) * COLS + c] = w.w;
  }
  __syncthreads();
  const int tx = t & 15, ty = t >> 4;
  const long rbase = (long)blockIdx.x * 128 + ty * 8;
  constexpr int NG = COLS / 64;
  float acc[8][NG * 4];
#pragma unroll
  for (int i = 0; i < 8; i++)
#pragma unroll
    for (int j = 0; j < NG * 4; j++) acc[i][j] = 0.0f;
  long ri[8];
#pragma unroll
  for (int i = 0; i < 8; i++) {
    long r = rbase + i;
    if (r > nrows - 1) r = nrows - 1;
    ri[i] = r;
  }
  for (int k0 = 0; k0 < 128; k0 += 4) {
    float4 xv[8];
#pragma unroll
    for (int i = 0; i < 8; i++) {
      const long a = INS ? sl_addr(ri[i], k0, sstr) : (ri[i] * 128 + k0);
      xv[i] = *(const float4*)(X + a);
    }
#pragma unroll
    for (int kk = 0; kk < 4; kk++) {
      float4 wv[NG];
#pragma unroll
      for (int g = 0; g < NG; g++)
        wv[g] = *(const float4*)(&Wt[(k0 + kk) * COLS + g * 64 + 4 * tx]);
#pragma unroll
      for (int i = 0; i < 8; i++) {
        const float xs = ((const float*)&xv[i])[kk];
#pragma unroll
        for (int g = 0; g < NG; g++) {
          acc[i][g * 4 + 0] = fmaf(xs, wv[g].x, acc[i][g * 4 + 0]);
          acc[i][g * 4 + 1] = fmaf(xs, wv[g].y, acc[i][g * 4 + 1]);
          acc[i][g * 4 + 2] = fmaf(xs, wv[g].z, acc[i][g * 4 + 2]);
          acc[i][g * 4 + 3] = fmaf(xs, wv[g].w, acc[i][g * 4 + 3]);
        }
      }
    }
  }
  float4 bv[NG];
#pragma unroll
  for (int g = 0; g < NG; g++) bv[g] = *(const float4*)(bias + g * 64 + 4 * tx);
#pragma unroll
  for (int i = 0; i < 8; i++) {
    const long r = rbase + i;
    if (r < nrows) {
#pragma unroll
      for (int g = 0; g < NG; g++) {
        float4 o;
        o.x = acc[i][g * 4 + 0] + bv[g].x;
        o.y = acc[i][g * 4 + 1] + bv[g].y;
        o.z = acc[i][g * 4 + 2] + bv[g].z;
        o.w = acc[i][g * 4 + 3] + bv[g].w;
        const int c = g * 64 + 4 * tx;
        const long a = OUTS ? sl_addr(r, c, sstr) : (r * COLS + c);
        *(float4*)(Y + a) = o;
      }
    }
  }
}

// ---------------------------------------------------------------------------
// Edge moment stats, slice-major. slice = blockIdx&7 (XCD round-robin).
// Wave = 8 node-groups x 8 lanes (lane owns a channel pair within slice).
// X is slice-major: row stride 16 within the slice block.
// ---------------------------------------------------------------------------
__global__ __launch_bounds__(256) void edge_stats_sliced(
    const float* __restrict__ X, const int* __restrict__ csr,
    const int* __restrict__ offs, int n, long sstr, float* __restrict__ stat) {
  __shared__ float lds_s[16];
  __shared__ float lds_q[16];
  const int t = threadIdx.x;
  const int sl = blockIdx.x & 7;
  const int nb = blockIdx.x >> 3;
  const int l = t & 63;
  const int c = l & 7, g = l >> 3;
  const int wq = nb * 4 + (t >> 6);
  const int base = wq * 8 + g;
  const int stride = (gridDim.x >> 3) * 4 * 8;
  const float* Xs = X + (long)sl * sstr + 2 * c;
  float s0 = 0.f, s1 = 0.f, q0 = 0.f, q1 = 0.f;
  for (int i = base; i < n; i += stride) {
    const int beg = offs[i], end = offs[i + 1];
    const float2 xd = *(const float2*)(Xs + (long)i * 16);
    int p = beg;
    for (; p + 4 <= end; p += 4) {
      int sx[4];
#pragma unroll
      for (int j = 0; j < 4; j++) sx[j] = __builtin_nontemporal_load(csr + p + j);
      float2 xa[4];
#pragma unroll
      for (int j = 0; j < 4; j++)
        xa[j] = *(const float2*)(Xs + (long)sx[j] * 16);
#pragma unroll
      for (int j = 0; j < 4; j++) {
        float d0 = xa[j].x - xd.x;
        d0 *= d0;
        float d1 = xa[j].y - xd.y;
        d1 *= d1;
        s0 += d0;
        q0 += d0 * d0;
        s1 += d1;
        q1 += d1 * d1;
      }
    }
    for (; p < end; ++p) {
      const int s = __builtin_nontemporal_load(csr + p);
      const float2 xa = *(const float2*)(Xs + (long)s * 16);
      float d0 = xa.x - xd.x;
      d0 *= d0;
      float d1 = xa.y - xd.y;
      d1 *= d1;
      s0 += d0;
      q0 += d0 * d0;
      s1 += d1;
      q1 += d1 * d1;
    }
  }
  if (t < 16) {
    lds_s[t] = 0.0f;
    lds_q[t] = 0.0f;
  }
  __syncthreads();
  atomicAdd(&lds_s[2 * c], s0);
  atomicAdd(&lds_s[2 * c + 1], s1);
  atomicAdd(&lds_q[2 * c], q0);
  atomicAdd(&lds_q[2 * c + 1], q1);
  __syncthreads();
  if (t < 16) {
    atomicAdd(&stat[sl * 16 + t], lds_s[t]);
    atomicAdd(&stat[128 + sl * 16 + t], lds_q[t]);
  }
}

// ---------------------------------------------------------------------------
// Attention vectors from stats. One block of 128 threads (thread = channel).
// ---------------------------------------------------------------------------
__global__ __launch_bounds__(128) void compute_att(
    const float* __restrict__ stat, const float* __restrict__ src_w,
    const float* __restrict__ src_b, const float* __restrict__ dst_w,
    const float* __restrict__ dst_b, const float* __restrict__ tq,
    float* __restrict__ att_l, float* __restrict__ att_r, float Ef) {
  const int c = threadIdx.x;
  __shared__ float red[4][128];
  const float sum = stat[c], sq = stat[128 + c];
  const float m1 = sum / Ef;
  float var = (sq - sum * (sum / Ef)) / (Ef - 1.0f);
  var = fmaxf(var, 0.0f);
  const float sd = sqrtf(var);
  const float m2 = sd + 1e-5f;
  float S[4];
  S[0] = m1;
  S[1] = sd;
  S[2] = (m1 * m1 * m1) / (m2 * m2 * m2);
  const float m12 = m1 * m1, m22 = m2 * m2;
  S[3] = (m12 * m12) / (m22 * m22);
#pragma unroll
  for (int j = 0; j < 4; j++) {
    if (isnan(S[j])) S[j] = 0.0f;
    S[j] = tanhf(S[j]);
    red[j][c] = S[j] * S[j];
  }
  for (int o = 64; o; o >>= 1) {
    __syncthreads();
    if (c < o) {
#pragma unroll
      for (int j = 0; j < 4; j++) red[j][c] += red[j][c + o];
    }
  }
  __syncthreads();
#pragma unroll
  for (int j = 0; j < 4; j++) S[j] /= fmaxf(sqrtf(red[j][0]), 1e-12f);
  float al = 0.0f, ar = 0.0f;
#pragma unroll
  for (int j = 0; j < 16; j++) {
    float tl = src_b[j], tr = dst_b[j];
#pragma unroll
    for (int k = 0; k < 4; k++) {
      tl += S[k] * src_w[j * 4 + k];
      tr += S[k] * dst_w[j * 4 + k];
    }
    al += tq[j] * tl;
    ar += tq[j] * tr;
  }
  att_l[c] = al;
  att_r[c] = ar;
}

// ---------------------------------------------------------------------------
// Per-node scores from slice-major X.
// ---------------------------------------------------------------------------
__global__ __launch_bounds__(256) void node_scores(
    const float* __restrict__ X, const float* __restrict__ attl,
    const float* __restrict__ attr, float* __restrict__ a_src,
    float* __restrict__ a_dst, int n, long sstr) {
  const int t = threadIdx.x, l = t & 63;
  const float2 al = ((const float2*)attl)[l];
  const float2 ar = ((const float2*)attr)[l];
  const long lbase = (long)(l >> 3) * sstr + 2 * (l & 7);
  const int wid = blockIdx.x * 4 + (t >> 6);
  const int nw = gridDim.x * 4;
  for (int i = wid; i < n; i += nw) {
    const float2 xv = *(const float2*)(X + lbase + (long)i * 16);
    float sl = xv.x * al.x + xv.y * al.y;
    float sr = xv.x * ar.x + xv.y * ar.y;
    sl = wave_sum(sl);
    sr = wave_sum(sr);
    if (l == 0) {
      a_src[i] = sl;
      a_dst[i] = sr;
    }
  }
}

// ---------------------------------------------------------------------------
// CSR build (by dst, self-loops included via deg init = 1)
// ---------------------------------------------------------------------------
__global__ void init_deg(int* deg, int n) {
  int i = blockIdx.x * 256 + threadIdx.x;
  if (i < n) deg[i] = 1;
}
__global__ void hist_dst(const int* __restrict__ edst, int E, int* deg) {
  int e = blockIdx.x * 256 + threadIdx.x;
  if (e < E) atomicAdd(&deg[edst[e]], 1);
}
__global__ __launch_bounds__(256) void scan_partial(const int* __restrict__ deg,
                                                    int n, int* bsum) {
  __shared__ int r[256];
  int t = threadIdx.x;
  int g = blockIdx.x * 256 + t;
  r[t] = (g < n) ? deg[g] : 0;
  for (int o = 128; o; o >>= 1) {
    __syncthreads();
    if (t < o) r[t] += r[t + o];
  }
  if (t == 0) bsum[blockIdx.x] = r[0];
}
__global__ __launch_bounds__(256) void scan_bsums(int* bsum, int nb) {
  __shared__ int r[256];
  int t = threadIdx.x;
  int v = (t < nb) ? bsum[t] : 0;
  r[t] = v;
  for (int o = 1; o < 256; o <<= 1) {
    int x = 0;
    __syncthreads();
    if (t >= o) x = r[t - o];
    __syncthreads();
    r[t] += x;
  }
  if (t < nb) bsum[t] = r[t] - v;  // exclusive
}
__global__ __launch_bounds__(256) void scan_final(const int* __restrict__ deg,
                                                  int n,
                                                  const int* __restrict__ bsum,
                                                  int* offs, int* cursor) {
  __shared__ int r[256];
  int t = threadIdx.x;
  int g = blockIdx.x * 256 + t;
  int v = (g < n) ? deg[g] : 0;
  r[t] = v;
  for (int o = 1; o < 256; o <<= 1) {
    int x = 0;
    __syncthreads();
    if (t >= o) x = r[t - o];
    __syncthreads();
    r[t] += x;
  }
  int excl = bsum[blockIdx.x] + r[t] - v;
  if (g < n) {
    offs[g] = excl;
    cursor[g] = excl;
    if (g == n - 1) offs[n] = excl + v;
  }
}
__global__ void scatter_csr(const int* __restrict__ esrc,
                            const int* __restrict__ edst, int E, int n,
                            int* cursor, int* __restrict__ csr) {
  int g = blockIdx.x * 256 + threadIdx.x;
  if (g < E) {
    int d = edst[g];
    int p = atomicAdd(&cursor[d], 1);
    csr[p] = esrc[g];
  } else if (g < E + n) {
    int i = g - E;
    int p = atomicAdd(&cursor[i], 1);
    csr[p] = i;
  }
}

// ---------------------------------------------------------------------------
// Softmax weights per CSR slot. Wave per node, lane-parallel (deg<=128 fast).
// ---------------------------------------------------------------------------
__global__ __launch_bounds__(256) void compute_alpha(
    const int* __restrict__ csr, const int* __restrict__ offs,
    const float* __restrict__ a_src, const float* __restrict__ a_dst,
    float* __restrict__ alpha, int n) {
  const int t = threadIdx.x, l = t & 63;
  const int wid = blockIdx.x * 4 + (t >> 6);
  const int nw = gridDim.x * 4;
  for (int i = wid; i < n; i += nw) {
    const int beg = offs[i], end = offs[i + 1], deg = end - beg;
    const float adsti = a_dst[i];
    if (deg <= 128) {
      float a0 = -INFINITY, a1 = -INFINITY;
      if (l < deg) {
        float a = a_src[csr[beg + l]] + adsti;
        a0 = (a > 0.0f ? a : 0.2f * a) * 0.1f;
      }
      if (64 + l < deg) {
        float a = a_src[csr[beg + 64 + l]] + adsti;
        a1 = (a > 0.0f ? a : 0.2f * a) * 0.1f;
      }
      const float mx = wave_max(fmaxf(a0, a1));
      const float e0 = expf(a0 - mx);
      const float e1 = expf(a1 - mx);
      const float sm = wave_sum(e0 + e1);
      const float inv = 1.0f / (sm + 1e-16f);
      if (l < deg) alpha[beg + l] = e0 * inv;
      if (64 + l < deg) alpha[beg + 64 + l] = e1 * inv;
    } else {
      float mx = -1e30f;
      for (int p = beg + l; p < end; p += 64) {
        float a = a_src[csr[p]] + adsti;
        a = (a > 0.0f ? a : 0.2f * a) * 0.1f;
        mx = fmaxf(mx, a);
      }
      mx = wave_max(mx);
      float sm = 0.0f;
      for (int p = beg + l; p < end; p += 64) {
        float a = a_src[csr[p]] + adsti;
        a = (a > 0.0f ? a : 0.2f * a) * 0.1f;
        sm += expf(a - mx);
      }
      sm = wave_sum(sm);
      const float inv = 1.0f / (sm + 1e-16f);
      for (int p = beg + l; p < end; p += 64) {
        float a = a_src[csr[p]] + adsti;
        a = (a > 0.0f ? a : 0.2f * a) * 0.1f;
        alpha[p] = expf(a - mx) * inv;
      }
    }
  }
}

// ---------------------------------------------------------------------------
// Weighted-sum gather, slice-major in AND out. slice = blockIdx&7.
// ---------------------------------------------------------------------------
__global__ __launch_bounds__(256) void aggregate_sliced(
    const float* __restrict__ X, const int* __restrict__ csr,
    const int* __restrict__ offs, const float* __restrict__ alpha,
    const float* __restrict__ bias, float* __restrict__ Y, int n, long sstr,
    int do_relu) {
  const int t = threadIdx.x;
  const int sl = blockIdx.x & 7;
  const int nb = blockIdx.x >> 3;
  const int l = t & 63;
  const int c = l & 7, g = l >> 3;
  const int wq = nb * 4 + (t >> 6);
  const int base = wq * 8 + g;
  const int stride = (gridDim.x >> 3) * 4 * 8;
  const float* Xs = X + (long)sl * sstr + 2 * c;
  float* Ys = Y + (long)sl * sstr + 2 * c;
  const float2 b2 = *(const float2*)(bias + sl * 16 + 2 * c);
  for (int i = base; i < n; i += stride) {
    const int beg = offs[i], end = offs[i + 1];
    float ax = 0.0f, ay = 0.0f;
    int p = beg;
    for (; p + 4 <= end; p += 4) {
      int sx[4];
      float w[4];
#pragma unroll
      for (int j = 0; j < 4; j++) {
        sx[j] = __builtin_nontemporal_load(csr + p + j);
        w[j] = __builtin_nontemporal_load(alpha + p + j);
      }
      float2 xa[4];
#pragma unroll
      for (int j = 0; j < 4; j++)
        xa[j] = *(const float2*)(Xs + (long)sx[j] * 16);
#pragma unroll
      for (int j = 0; j < 4; j++) {
        ax = fmaf(w[j], xa[j].x, ax);
        ay = fmaf(w[j], xa[j].y, ay);
      }
    }
    for (; p < end; ++p) {
      const int s = __builtin_nontemporal_load(csr + p);
      const float w = __builtin_nontemporal_load(alpha + p);
      const float2 xa = *(const float2*)(Xs + (long)s * 16);
      ax = fmaf(w, xa.x, ax);
      ay = fmaf(w, xa.y, ay);
    }
    float ox = ax + b2.x, oy = ay + b2.y;
    if (do_relu) {
      ox = fmaxf(ox, 0.0f);
      oy = fmaxf(oy, 0.0f);
    }
    *(float2*)(Ys + (long)i * 16) = make_float2(ox, oy);
  }
}

// ---------------------------------------------------------------------------
extern "C" void kernel_launch(void* const* d_in, const int* in_sizes, int n_in,
                              void* d_out, int out_size, void* d_ws,
                              size_t ws_size, hipStream_t stream) {
  (void)n_in;
  (void)out_size;
  (void)ws_size;
  const float* x = (const float*)d_in[0];
  const int* ei = (const int*)d_in[1];
  const float* W0 = (const float*)d_in[2];
  const float* b0 = (const float*)d_in[3];
  const float* W2 = (const float*)d_in[4];
  const float* b2 = (const float*)d_in[5];
  const float* gsw[2] = {(const float*)d_in[6], (const float*)d_in[12]};
  const float* gsb[2] = {(const float*)d_in[7], (const float*)d_in[13]};
  const float* gdw[2] = {(const float*)d_in[8], (const float*)d_in[14]};
  const float* gdb[2] = {(const float*)d_in[9], (const float*)d_in[15]};
  const float* gtq[2] = {(const float*)d_in[10], (const float*)d_in[16]};
  const float* gbias[2] = {(const float*)d_in[11], (const float*)d_in[17]};

  const int N = in_sizes[0] / 128;
  const int E = in_sizes[1] / 2;
  const int* esrc = ei;
  const int* edst = ei + E;
  const long sstr = (long)N * 16;  // slice stride (elements)

  float* ws = (float*)d_ws;
  size_t o = 0;
  float* h0 = ws + o;
  o += (size_t)N * 128;
  float* h1 = ws + o;
  o += (size_t)N * 128;
  float* stat = ws + o;
  o += 256;
  float* attl = ws + o;
  o += 128;
  float* attr = ws + o;
  o += 128;
  float* a_src = ws + o;
  o += N;
  float* a_dst = ws + o;
  o += N;
  float* alpha = ws + o;
  o += (size_t)E + N;
  int* ip = (int*)(ws + o);
  int* deg = ip;
  ip += N;
  int* offs = ip;
  ip += N + 1;
  int* cursor = ip;
  ip += N;
  int* bsum = ip;
  ip += 256;
  int* csr = ip;
  ip += E + N;

  const int NB = (N + 255) / 256;  // 196 <= 256 required by scan_bsums

  // GEMM1: h0 = x @ W0^T + b0   (row-major in, slice-major out)
  gemm_bias<128, false, true><<<(N + 127) / 128, 256, 0, stream>>>(
      x, W0, b0, h0, N, sstr);

  // CSR build (shared by both convs)
  init_deg<<<NB, 256, 0, stream>>>(deg, N);
  hist_dst<<<(E + 255) / 256, 256, 0, stream>>>(edst, E, deg);
  scan_partial<<<NB, 256, 0, stream>>>(deg, N, bsum);
  scan_bsums<<<1, 256, 0, stream>>>(bsum, NB);
  scan_final<<<NB, 256, 0, stream>>>(deg, N, bsum, offs, cursor);
  scatter_csr<<<(E + N + 255) / 256, 256, 0, stream>>>(esrc, edst, E, N,
                                                       cursor, csr);

  for (int layer = 0; layer < 2; ++layer) {
    const float* Xc = layer ? h1 : h0;
    float* Yc = layer ? h0 : h1;
    hipMemsetAsync(stat, 0, 256 * sizeof(float), stream);
    edge_stats_sliced<<<2048, 256, 0, stream>>>(Xc, csr, offs, N, sstr, stat);
    compute_att<<<1, 128, 0, stream>>>(stat, gsw[layer], gsb[layer],
                                       gdw[layer], gdb[layer], gtq[layer],
                                       attl, attr, (float)E);
    node_scores<<<1024, 256, 0, stream>>>(Xc, attl, attr, a_src, a_dst, N,
                                          sstr);
    compute_alpha<<<1024, 256, 0, stream>>>(csr, offs, a_src, a_dst, alpha, N);
    aggregate_sliced<<<2048, 256, 0, stream>>>(Xc, csr, offs, alpha,
                                               gbias[layer], Yc, N, sstr,
                                               layer == 0 ? 1 : 0);
  }

  // GEMM2: out = h0 @ W2^T + b2   (slice-major in, row-major out)
  gemm_bias<64, true, false><<<(N + 127) / 128, 256, 0, stream>>>(
      h0, W2, b2, (float*)d_out, N, sstr);
}

// Round 5
// 528.553 us; speedup vs baseline: 1.4555x; 1.4555x over previous
//
#include <hip/hip_runtime.h>
#include <math.h>

// ---------------------------------------------------------------------------
// SPA graph conv, 2 layers. N=50000, E=800000, C=128, OUT=64, HS=16, K=4.
// R5: revert to R2 structure (wave-per-node, register-broadcast softmax —
//     L2-slicing of R3/R4 regressed). New: bf16 SHADOW COPIES of conv inputs
//     for the 4 edge-gather passes (stats + aggregate x 2 layers): halves
//     gathered bytes. All accumulation and primary activations stay fp32.
// ---------------------------------------------------------------------------

__device__ __forceinline__ float wave_max(float v) {
#pragma unroll
  for (int o = 32; o; o >>= 1) v = fmaxf(v, __shfl_xor(v, o, 64));
  return v;
}
__device__ __forceinline__ float wave_sum(float v) {
#pragma unroll
  for (int o = 32; o; o >>= 1) v += __shfl_xor(v, o, 64);
  return v;
}

// bf16 pair packed in a uint: low ushort = even channel, high = odd channel.
__device__ __forceinline__ float bflo(unsigned u) {
  return __uint_as_float(u << 16);
}
__device__ __forceinline__ float bfhi(unsigned u) {
  return __uint_as_float(u & 0xffff0000u);
}
__device__ __forceinline__ unsigned f2bf(float f) {  // RNE
  unsigned x = __float_as_uint(f);
  return (x + 0x7fffu + ((x >> 16) & 1u)) >> 16;
}
__device__ __forceinline__ unsigned packbf(float a, float b) {
  return f2bf(a) | (f2bf(b) << 16);
}

// ---------------------------------------------------------------------------
// GEMM: Y[r][c] = sum_k X[r][k]*W[c][k] + bias[c].  K fixed = 128.
// BFOUT additionally writes a bf16 shadow copy (row-major, uint = ch pair).
// ---------------------------------------------------------------------------
template <int COLS, bool BFOUT>
__global__ __launch_bounds__(256) void gemm_bias(
    const float* __restrict__ X, const float* __restrict__ W,
    const float* __restrict__ bias, float* __restrict__ Y,
    unsigned* __restrict__ Yb, int nrows) {
  __shared__ float Wt[128 * COLS];
  const int t = threadIdx.x;
  for (int q = t; q < COLS * 32; q += 256) {
    const int c = q >> 5;
    const int k0 = (q & 31) << 2;
    const float4 w = *(const float4*)(W + c * 128 + k0);
    Wt[(k0 + 0) * COLS + c] = w.x;
    Wt[(k0 + 1) * COLS + c] = w.y;
    Wt[(k0 + 2) * COLS + c] = w.z;
    Wt[(k0 + 3) * COLS + c] = w.w;
  }
  __syncthreads();
  const int tx = t & 15, ty = t >> 4;
  const long rbase = (long)blockIdx.x * 128 + ty * 8;
  constexpr int NG = COLS / 64;
  float acc[8][NG * 4];
#pragma unroll
  for (int i = 0; i < 8; i++)
#pragma unroll
    for (int j = 0; j < NG * 4; j++) acc[i][j] = 0.0f;
  const float* xp[8];
#pragma unroll
  for (int i = 0; i < 8; i++) {
    long r = rbase + i;
    if (r > nrows - 1) r = nrows - 1;
    xp[i] = X + r * 128;
  }
  for (int k0 = 0; k0 < 128; k0 += 4) {
    float4 xv[8];
#pragma unroll
    for (int i = 0; i < 8; i++) xv[i] = *(const float4*)(xp[i] + k0);
#pragma unroll
    for (int kk = 0; kk < 4; kk++) {
      float4 wv[NG];
#pragma unroll
      for (int g = 0; g < NG; g++)
        wv[g] = *(const float4*)(&Wt[(k0 + kk) * COLS + g * 64 + 4 * tx]);
#pragma unroll
      for (int i = 0; i < 8; i++) {
        const float xs = ((const float*)&xv[i])[kk];
#pragma unroll
        for (int g = 0; g < NG; g++) {
          acc[i][g * 4 + 0] = fmaf(xs, wv[g].x, acc[i][g * 4 + 0]);
          acc[i][g * 4 + 1] = fmaf(xs, wv[g].y, acc[i][g * 4 + 1]);
          acc[i][g * 4 + 2] = fmaf(xs, wv[g].z, acc[i][g * 4 + 2]);
          acc[i][g * 4 + 3] = fmaf(xs, wv[g].w, acc[i][g * 4 + 3]);
        }
      }
    }
  }
  float4 bv[NG];
#pragma unroll
  for (int g = 0; g < NG; g++) bv[g] = *(const float4*)(bias + g * 64 + 4 * tx);
#pragma unroll
  for (int i = 0; i < 8; i++) {
    const long r = rbase + i;
    if (r < nrows) {
#pragma unroll
      for (int g = 0; g < NG; g++) {
        float4 o;
        o.x = acc[i][g * 4 + 0] + bv[g].x;
        o.y = acc[i][g * 4 + 1] + bv[g].y;
        o.z = acc[i][g * 4 + 2] + bv[g].z;
        o.w = acc[i][g * 4 + 3] + bv[g].w;
        const int c = g * 64 + 4 * tx;
        *(float4*)(Y + r * COLS + c) = o;
        if (BFOUT) {
          uint2 p;
          p.x = packbf(o.x, o.y);
          p.y = packbf(o.z, o.w);
          *(uint2*)(Yb + r * (COLS / 2) + (c >> 1)) = p;
        }
      }
    }
  }
}

// ---------------------------------------------------------------------------
// Edge moment stats via CSR, bf16 gather. Wave per dst node; dst row loaded
// once; src indices broadcast from registers; x4 unrolled independent loads.
// Self-loop entries contribute exactly 0; denominator Ef=E downstream.
// ---------------------------------------------------------------------------
__global__ __launch_bounds__(256) void edge_stats_bf(
    const unsigned* __restrict__ Xb, const int* __restrict__ csr,
    const int* __restrict__ offs, int n, float* __restrict__ stat) {
  __shared__ float pS[4][128];
  __shared__ float pQ[4][128];
  const int t = threadIdx.x;
  const int w = t >> 6, l = t & 63;
  const int wid = blockIdx.x * 4 + w;
  const int nw = gridDim.x * 4;
  float s0 = 0.f, q0 = 0.f, s1 = 0.f, q1 = 0.f;
  for (int i = wid; i < n; i += nw) {
    const int beg = offs[i], end = offs[i + 1];
    const int deg = end - beg;
    const unsigned ud = Xb[(long)i * 64 + l];
    const float xd0 = bflo(ud), xd1 = bfhi(ud);
    if (deg <= 128) {
      int s0r = 0, s1r = 0;
      if (l < deg) s0r = csr[beg + l];
      if (64 + l < deg) s1r = csr[beg + 64 + l];
      int k = 0;
      for (; k + 4 <= deg; k += 4) {
        int sx[4];
#pragma unroll
        for (int j = 0; j < 4; j++) {
          const int kk = k + j;
          sx[j] = __shfl(kk < 64 ? s0r : s1r, kk & 63);
        }
        unsigned ua[4];
#pragma unroll
        for (int j = 0; j < 4; j++) ua[j] = Xb[(long)sx[j] * 64 + l];
#pragma unroll
        for (int j = 0; j < 4; j++) {
          float d0 = bflo(ua[j]) - xd0;
          d0 *= d0;
          float d1 = bfhi(ua[j]) - xd1;
          d1 *= d1;
          s0 += d0;
          q0 += d0 * d0;
          s1 += d1;
          q1 += d1 * d1;
        }
      }
      for (; k < deg; ++k) {
        const int s = __shfl(k < 64 ? s0r : s1r, k & 63);
        const unsigned ua = Xb[(long)s * 64 + l];
        float d0 = bflo(ua) - xd0;
        d0 *= d0;
        float d1 = bfhi(ua) - xd1;
        d1 *= d1;
        s0 += d0;
        q0 += d0 * d0;
        s1 += d1;
        q1 += d1 * d1;
      }
    } else {
      for (int p = beg; p < end; ++p) {
        const int s = csr[p];
        const unsigned ua = Xb[(long)s * 64 + l];
        float d0 = bflo(ua) - xd0;
        d0 *= d0;
        float d1 = bfhi(ua) - xd1;
        d1 *= d1;
        s0 += d0;
        q0 += d0 * d0;
        s1 += d1;
        q1 += d1 * d1;
      }
    }
  }
  pS[w][2 * l] = s0;
  pS[w][2 * l + 1] = s1;
  pQ[w][2 * l] = q0;
  pQ[w][2 * l + 1] = q1;
  __syncthreads();
  if (t < 128) {
    atomicAdd(&stat[t], pS[0][t] + pS[1][t] + pS[2][t] + pS[3][t]);
  } else {
    const int c = t - 128;
    atomicAdd(&stat[128 + c], pQ[0][c] + pQ[1][c] + pQ[2][c] + pQ[3][c]);
  }
}

// ---------------------------------------------------------------------------
// Attention vectors from stats. One block of 128 threads (thread = channel).
// ---------------------------------------------------------------------------
__global__ __launch_bounds__(128) void compute_att(
    const float* __restrict__ stat, const float* __restrict__ src_w,
    const float* __restrict__ src_b, const float* __restrict__ dst_w,
    const float* __restrict__ dst_b, const float* __restrict__ tq,
    float* __restrict__ att_l, float* __restrict__ att_r, float Ef) {
  const int c = threadIdx.x;
  __shared__ float red[4][128];
  const float sum = stat[c], sq = stat[128 + c];
  const float m1 = sum / Ef;
  float var = (sq - sum * (sum / Ef)) / (Ef - 1.0f);
  var = fmaxf(var, 0.0f);
  const float sd = sqrtf(var);
  const float m2 = sd + 1e-5f;
  float S[4];
  S[0] = m1;
  S[1] = sd;
  S[2] = (m1 * m1 * m1) / (m2 * m2 * m2);
  const float m12 = m1 * m1, m22 = m2 * m2;
  S[3] = (m12 * m12) / (m22 * m22);
#pragma unroll
  for (int j = 0; j < 4; j++) {
    if (isnan(S[j])) S[j] = 0.0f;
    S[j] = tanhf(S[j]);
    red[j][c] = S[j] * S[j];
  }
  for (int o = 64; o; o >>= 1) {
    __syncthreads();
    if (c < o) {
#pragma unroll
      for (int j = 0; j < 4; j++) red[j][c] += red[j][c + o];
    }
  }
  __syncthreads();
#pragma unroll
  for (int j = 0; j < 4; j++) S[j] /= fmaxf(sqrtf(red[j][0]), 1e-12f);
  float al = 0.0f, ar = 0.0f;
#pragma unroll
  for (int j = 0; j < 16; j++) {
    float tl = src_b[j], tr = dst_b[j];
#pragma unroll
    for (int k = 0; k < 4; k++) {
      tl += S[k] * src_w[j * 4 + k];
      tr += S[k] * dst_w[j * 4 + k];
    }
    al += tq[j] * tl;
    ar += tq[j] * tr;
  }
  att_l[c] = al;
  att_r[c] = ar;
}

// ---------------------------------------------------------------------------
// Per-node scores (fp32 stream): a_src=dot(X,att_l), a_dst=dot(X,att_r).
// ---------------------------------------------------------------------------
__global__ __launch_bounds__(256) void node_scores(
    const float* __restrict__ X, const float* __restrict__ attl,
    const float* __restrict__ attr, float* __restrict__ a_src,
    float* __restrict__ a_dst, int n) {
  const int t = threadIdx.x, l = t & 63;
  const float2 al = ((const float2*)attl)[l];
  const float2 ar = ((const float2*)attr)[l];
  const int wid = blockIdx.x * 4 + (t >> 6);
  const int nw = gridDim.x * 4;
  for (int i = wid; i < n; i += nw) {
    const float2 xv = ((const float2*)(X + (long)i * 128))[l];
    float sl = xv.x * al.x + xv.y * al.y;
    float sr = xv.x * ar.x + xv.y * ar.y;
    sl = wave_sum(sl);
    sr = wave_sum(sr);
    if (l == 0) {
      a_src[i] = sl;
      a_dst[i] = sr;
    }
  }
}

// ---------------------------------------------------------------------------
// CSR build (by dst, self-loops included via deg init = 1)
// ---------------------------------------------------------------------------
__global__ void init_deg(int* deg, int n) {
  int i = blockIdx.x * 256 + threadIdx.x;
  if (i < n) deg[i] = 1;
}
__global__ void hist_dst(const int* __restrict__ edst, int E, int* deg) {
  int e = blockIdx.x * 256 + threadIdx.x;
  if (e < E) atomicAdd(&deg[edst[e]], 1);
}
__global__ __launch_bounds__(256) void scan_partial(const int* __restrict__ deg,
                                                    int n, int* bsum) {
  __shared__ int r[256];
  int t = threadIdx.x;
  int g = blockIdx.x * 256 + t;
  r[t] = (g < n) ? deg[g] : 0;
  for (int o = 128; o; o >>= 1) {
    __syncthreads();
    if (t < o) r[t] += r[t + o];
  }
  if (t == 0) bsum[blockIdx.x] = r[0];
}
__global__ __launch_bounds__(256) void scan_bsums(int* bsum, int nb) {
  __shared__ int r[256];
  int t = threadIdx.x;
  int v = (t < nb) ? bsum[t] : 0;
  r[t] = v;
  for (int o = 1; o < 256; o <<= 1) {
    int x = 0;
    __syncthreads();
    if (t >= o) x = r[t - o];
    __syncthreads();
    r[t] += x;
  }
  if (t < nb) bsum[t] = r[t] - v;  // exclusive
}
__global__ __launch_bounds__(256) void scan_final(const int* __restrict__ deg,
                                                  int n,
                                                  const int* __restrict__ bsum,
                                                  int* offs, int* cursor) {
  __shared__ int r[256];
  int t = threadIdx.x;
  int g = blockIdx.x * 256 + t;
  int v = (g < n) ? deg[g] : 0;
  r[t] = v;
  for (int o = 1; o < 256; o <<= 1) {
    int x = 0;
    __syncthreads();
    if (t >= o) x = r[t - o];
    __syncthreads();
    r[t] += x;
  }
  int excl = bsum[blockIdx.x] + r[t] - v;
  if (g < n) {
    offs[g] = excl;
    cursor[g] = excl;
    if (g == n - 1) offs[n] = excl + v;
  }
}
__global__ void scatter_csr(const int* __restrict__ esrc,
                            const int* __restrict__ edst, int E, int n,
                            int* cursor, int* __restrict__ csr) {
  int g = blockIdx.x * 256 + threadIdx.x;
  if (g < E) {
    int d = edst[g];
    int p = atomicAdd(&cursor[d], 1);
    csr[p] = esrc[g];
  } else if (g < E + n) {
    int i = g - E;
    int p = atomicAdd(&cursor[i], 1);
    csr[p] = i;
  }
}

// ---------------------------------------------------------------------------
// Softmax aggregation, bf16 gather. Wave per dst node (R2 structure):
// lane-parallel softmax once, then serial accumulate with (src,alpha)
// broadcast from registers; only memory op in loop = independent bf16 row
// load (uint/lane = 2 channels), unrolled x4. fp32 out + optional bf16 copy.
// ---------------------------------------------------------------------------
__global__ __launch_bounds__(256) void aggregate_bf(
    const unsigned* __restrict__ Xb, const int* __restrict__ csr,
    const int* __restrict__ offs, const float* __restrict__ a_src,
    const float* __restrict__ a_dst, const float* __restrict__ bias,
    float* __restrict__ Y, unsigned* __restrict__ Yb, int n, int do_relu,
    int write_bf) {
  const int t = threadIdx.x;
  const int l = t & 63;
  const int wid = blockIdx.x * 4 + (t >> 6);
  const int nw = gridDim.x * 4;
  const float2 b2 = ((const float2*)bias)[l];
  for (int i = wid; i < n; i += nw) {
    const int beg = offs[i], end = offs[i + 1];
    const int deg = end - beg;
    const float adsti = a_dst[i];
    float ax = 0.0f, ay = 0.0f;
    if (deg <= 128) {
      int s0r = 0, s1r = 0;
      float a0 = -INFINITY, a1 = -INFINITY;
      if (l < deg) {
        s0r = csr[beg + l];
        float a = a_src[s0r] + adsti;
        a0 = (a > 0.0f ? a : 0.2f * a) * 0.1f;
      }
      if (64 + l < deg) {
        s1r = csr[beg + 64 + l];
        float a = a_src[s1r] + adsti;
        a1 = (a > 0.0f ? a : 0.2f * a) * 0.1f;
      }
      const float mx = wave_max(fmaxf(a0, a1));
      const float e0 = expf(a0 - mx);
      const float e1 = expf(a1 - mx);
      const float sm = wave_sum(e0 + e1);
      const float inv = 1.0f / (sm + 1e-16f);
      const float al0 = e0 * inv, al1 = e1 * inv;
      int k = 0;
      for (; k + 4 <= deg; k += 4) {
        int sx[4];
        float wv[4];
#pragma unroll
        for (int j = 0; j < 4; j++) {
          const int kk = k + j;
          sx[j] = __shfl(kk < 64 ? s0r : s1r, kk & 63);
          wv[j] = __shfl(kk < 64 ? al0 : al1, kk & 63);
        }
        unsigned ua[4];
#pragma unroll
        for (int j = 0; j < 4; j++) ua[j] = Xb[(long)sx[j] * 64 + l];
#pragma unroll
        for (int j = 0; j < 4; j++) {
          ax = fmaf(wv[j], bflo(ua[j]), ax);
          ay = fmaf(wv[j], bfhi(ua[j]), ay);
        }
      }
      for (; k < deg; ++k) {
        const int s = __shfl(k < 64 ? s0r : s1r, k & 63);
        const float w = __shfl(k < 64 ? al0 : al1, k & 63);
        const unsigned ua = Xb[(long)s * 64 + l];
        ax = fmaf(w, bflo(ua), ax);
        ay = fmaf(w, bfhi(ua), ay);
      }
    } else {
      float mx = -1e30f;
      for (int p = beg + l; p < end; p += 64) {
        float a = a_src[csr[p]] + adsti;
        a = (a > 0.0f ? a : 0.2f * a) * 0.1f;
        mx = fmaxf(mx, a);
      }
      mx = wave_max(mx);
      float sm = 0.0f;
      for (int p = beg + l; p < end; p += 64) {
        float a = a_src[csr[p]] + adsti;
        a = (a > 0.0f ? a : 0.2f * a) * 0.1f;
        sm += expf(a - mx);
      }
      sm = wave_sum(sm);
      const float inv = 1.0f / (sm + 1e-16f);
      for (int p = beg; p < end; ++p) {
        const int s = csr[p];
        float a = a_src[s] + adsti;
        a = (a > 0.0f ? a : 0.2f * a) * 0.1f;
        const float alpha = expf(a - mx) * inv;
        const unsigned ua = Xb[(long)s * 64 + l];
        ax = fmaf(alpha, bflo(ua), ax);
        ay = fmaf(alpha, bfhi(ua), ay);
      }
    }
    float ox = ax + b2.x, oy = ay + b2.y;
    if (do_relu) {
      ox = fmaxf(ox, 0.0f);
      oy = fmaxf(oy, 0.0f);
    }
    ((float2*)(Y + (long)i * 128))[l] = make_float2(ox, oy);
    if (write_bf) Yb[(long)i * 64 + l] = packbf(ox, oy);
  }
}

// ---------------------------------------------------------------------------
extern "C" void kernel_launch(void* const* d_in, const int* in_sizes, int n_in,
                              void* d_out, int out_size, void* d_ws,
                              size_t ws_size, hipStream_t stream) {
  (void)n_in;
  (void)out_size;
  (void)ws_size;
  const float* x = (const float*)d_in[0];
  const int* ei = (const int*)d_in[1];
  const float* W0 = (const float*)d_in[2];
  const float* b0 = (const float*)d_in[3];
  const float* W2 = (const float*)d_in[4];
  const float* b2 = (const float*)d_in[5];
  const float* gsw[2] = {(const float*)d_in[6], (const float*)d_in[12]};
  const float* gsb[2] = {(const float*)d_in[7], (const float*)d_in[13]};
  const float* gdw[2] = {(const float*)d_in[8], (const float*)d_in[14]};
  const float* gdb[2] = {(const float*)d_in[9], (const float*)d_in[15]};
  const float* gtq[2] = {(const float*)d_in[10], (const float*)d_in[16]};
  const float* gbias[2] = {(const float*)d_in[11], (const float*)d_in[17]};

  const int N = in_sizes[0] / 128;
  const int E = in_sizes[1] / 2;
  const int* esrc = ei;
  const int* edst = ei + E;

  float* ws = (float*)d_ws;
  size_t o = 0;
  float* h0 = ws + o;
  o += (size_t)N * 128;
  float* h1 = ws + o;
  o += (size_t)N * 128;
  unsigned* h0b = (unsigned*)(ws + o);
  o += (size_t)N * 64;
  unsigned* h1b = (unsigned*)(ws + o);
  o += (size_t)N * 64;
  float* stat = ws + o;
  o += 256;
  float* attl = ws + o;
  o += 128;
  float* attr = ws + o;
  o += 128;
  float* a_src = ws + o;
  o += N;
  float* a_dst = ws + o;
  o += N;
  int* ip = (int*)(ws + o);
  int* deg = ip;
  ip += N;
  int* offs = ip;
  ip += N + 1;
  int* cursor = ip;
  ip += N;
  int* bsum = ip;
  ip += 256;
  int* csr = ip;
  ip += E + N;

  const int NB = (N + 255) / 256;  // 196 <= 256 required by scan_bsums

  // GEMM1: h0 = x @ W0^T + b0  (+ bf16 shadow h0b)
  gemm_bias<128, true><<<(N + 127) / 128, 256, 0, stream>>>(x, W0, b0, h0,
                                                            h0b, N);

  // CSR build (shared by both convs)
  init_deg<<<NB, 256, 0, stream>>>(deg, N);
  hist_dst<<<(E + 255) / 256, 256, 0, stream>>>(edst, E, deg);
  scan_partial<<<NB, 256, 0, stream>>>(deg, N, bsum);
  scan_bsums<<<1, 256, 0, stream>>>(bsum, NB);
  scan_final<<<NB, 256, 0, stream>>>(deg, N, bsum, offs, cursor);
  scatter_csr<<<(E + N + 255) / 256, 256, 0, stream>>>(esrc, edst, E, N,
                                                       cursor, csr);

  for (int layer = 0; layer < 2; ++layer) {
    const float* Xf = layer ? h1 : h0;
    const unsigned* Xb = layer ? h1b : h0b;
    float* Yf = layer ? h0 : h1;
    unsigned* Yb = layer ? h0b : h1b;  // only written for layer 0
    hipMemsetAsync(stat, 0, 256 * sizeof(float), stream);
    edge_stats_bf<<<2048, 256, 0, stream>>>(Xb, csr, offs, N, stat);
    compute_att<<<1, 128, 0, stream>>>(stat, gsw[layer], gsb[layer],
                                       gdw[layer], gdb[layer], gtq[layer],
                                       attl, attr, (float)E);
    node_scores<<<1024, 256, 0, stream>>>(Xf, attl, attr, a_src, a_dst, N);
    aggregate_bf<<<2048, 256, 0, stream>>>(Xb, csr, offs, a_src, a_dst,
                                           gbias[layer], Yf, Yb, N,
                                           layer == 0 ? 1 : 0,
                                           layer == 0 ? 1 : 0);
  }

  // GEMM2: out = h0 @ W2^T + b2   (h0 holds conv2 output, fp32)
  gemm_bias<64, false><<<(N + 127) / 128, 256, 0, stream>>>(
      h0, W2, b2, (float*)d_out, nullptr, N);
}